// Round 4
// baseline (424.707 us; speedup 1.0000x reference)
//
#include <hip/hip_runtime.h>

typedef float f32x4 __attribute__((ext_vector_type(4)));
typedef short bf16x8 __attribute__((ext_vector_type(8)));

// ---------- helpers ----------
__device__ __forceinline__ unsigned int pk2(float a, float b) {
    unsigned int ua = __float_as_uint(a); ua += 0x7FFFu + ((ua >> 16) & 1u);
    unsigned int ub = __float_as_uint(b); ub += 0x7FFFu + ((ub >> 16) & 1u);
    return __builtin_amdgcn_perm(ub, ua, 0x07060302u);
}
__device__ __forceinline__ unsigned short bf16_rne(float a) {
    unsigned int ua = __float_as_uint(a);
    ua += 0x7FFFu + ((ua >> 16) & 1u);
    return (unsigned short)(ua >> 16);
}
__device__ __forceinline__ float tanh_fast(float x) {
    float e = __expf(x + x);
    return 1.f - 2.f / (e + 1.f);
}
__device__ __forceinline__ f32x4 mfma16(bf16x8 a, bf16x8 b, f32x4 c) {
    return __builtin_amdgcn_mfma_f32_16x16x32_bf16(a, b, c, 0, 0, 0);
}
__device__ __forceinline__ bf16x8 as_bf(uint4 u) {
    bf16x8 r; __builtin_memcpy(&r, &u, 16); return r;
}
__device__ __forceinline__ bf16x8 cvt_bf(float4 v0, float4 v1) {
    uint4 u;
    u.x = pk2(v0.x, v0.y); u.y = pk2(v0.z, v0.w);
    u.z = pk2(v1.x, v1.y); u.w = pk2(v1.z, v1.w);
    return as_bf(u);
}

// ---------- 1. prep: weight conversion + location conv (weights only, no annots) ----------
#define Q_WIH   786432
#define Q_WHH   1572864
#define Q_QW    1703936
#define Q_X2    1720320
#define Q_X1    1736704
#define Q_BAW   1802240
#define Q_BLW   1806336
#define Q_EB    1806464
#define NB_CVT  7057

__global__ __launch_bounds__(256) void k_prep(
    const float* __restrict__ Wih, const float* __restrict__ Whh,
    const float* __restrict__ qw, const float* __restrict__ rnn_state,
    const float* __restrict__ memory, const float* __restrict__ context,
    const float* __restrict__ aw, const float* __restrict__ lw,
    const float* __restrict__ ab, const float* __restrict__ lb,
    const float* __restrict__ atten, const float* __restrict__ convw,
    unsigned short* __restrict__ Wihb, unsigned short* __restrict__ Whhb,
    unsigned short* __restrict__ qwb, unsigned short* __restrict__ X2b,
    unsigned short* __restrict__ X1b, unsigned short* __restrict__ Bbig,
    float* __restrict__ ebias, unsigned short* __restrict__ Lconv)
{
    __shared__ float att_s[2 * 160];
    __shared__ float cw_s[1984];
    const int tid = threadIdx.x;
    if (blockIdx.x < NB_CVT) {
        int q = blockIdx.x * 256 + tid;
        if (q >= Q_EB) return;
        if (q < Q_WIH) {
            int i = q * 4;
            float4 v = *(const float4*)(Wih + i);
            uint2 u; u.x = pk2(v.x, v.y); u.y = pk2(v.z, v.w);
            *(uint2*)(Wihb + i) = u;
        } else if (q < Q_WHH) {
            int i = (q - Q_WIH) * 4;
            float4 v = *(const float4*)(Whh + i);
            uint2 u; u.x = pk2(v.x, v.y); u.y = pk2(v.z, v.w);
            *(uint2*)(Whhb + i) = u;
        } else if (q < Q_QW) {
            int i = (q - Q_WHH) * 4;
            float4 v = *(const float4*)(qw + i);
            uint2 u; u.x = pk2(v.x, v.y); u.y = pk2(v.z, v.w);
            *(uint2*)(qwb + i) = u;
        } else if (q < Q_X2) {
            int i = (q - Q_QW) * 4;
            float4 v = *(const float4*)(rnn_state + i);
            uint2 u; u.x = pk2(v.x, v.y); u.y = pk2(v.z, v.w);
            *(uint2*)(X2b + i) = u;
        } else if (q < Q_X1) {
            int i = (q - Q_X2) * 4;
            int b = i >> 10, c = i & 1023;
            const float* s = (c < 512) ? (memory + b * 512 + c) : (context + b * 512 + (c - 512));
            float4 v = *(const float4*)s;
            uint2 u; u.x = pk2(v.x, v.y); u.y = pk2(v.z, v.w);
            *(uint2*)(X1b + i) = u;
        } else if (q < Q_BAW) {
            int i = (q - Q_X1) * 4;
            int a = i >> 9, c = i & 511;
            float4 v = *(const float4*)(aw + a * 512 + c);
            uint2 u; u.x = pk2(v.x, v.y); u.y = pk2(v.z, v.w);
            *(uint2*)(Bbig + a * 544 + c) = u;
        } else if (q < Q_BLW) {
            int i = (q - Q_BAW) * 4;
            int a = i >> 5, c = i & 31;
            float4 v = *(const float4*)(lw + a * 32 + c);
            uint2 u; u.x = pk2(v.x, v.y); u.y = pk2(v.z, v.w);
            *(uint2*)(Bbig + a * 544 + 512 + c) = u;
        } else {
            int i = (q - Q_BLW) * 4;
            float4 va = *(const float4*)(ab + i);
            float4 vb = *(const float4*)(lb + i);
            float4 r; r.x = va.x + vb.x; r.y = va.y + vb.y; r.z = va.z + vb.z; r.w = va.w + vb.w;
            *(float4*)(ebias + i) = r;
        }
    } else {
        const int bid = blockIdx.x - NB_CVT;
        const int b = bid >> 3;
        const int tbase = (bid & 7) * 128;
        for (int i = tid; i < 320; i += 256) {
            int c = i / 160, j = i % 160;
            float v = 0.f;
            int pos = tbase - 15 + j;
            if (j < 158 && pos >= 0 && pos < 1024) v = atten[b * 2048 + c * 1024 + pos];
            att_s[c * 160 + j] = v;
        }
        for (int i = tid; i < 1984; i += 256) cw_s[i] = convw[i];
        __syncthreads();
        const int f = tid & 31, tq = tid >> 5;
        float acc[16];
#pragma unroll
        for (int i = 0; i < 16; ++i) acc[i] = 0.f;
        for (int c = 0; c < 2; ++c) {
            for (int k = 0; k < 31; ++k) {
                float w = cw_s[f * 62 + c * 31 + k];
                int base = c * 160 + tq * 16 + k;
#pragma unroll
                for (int ti = 0; ti < 16; ++ti) acc[ti] += w * att_s[base + ti];
            }
        }
#pragma unroll
        for (int ti = 0; ti < 16; ++ti) {
            int t = tbase + tq * 16 + ti;
            Lconv[(b * 1024 + t) * 32 + f] = bf16_rne(acc[ti]);
        }
    }
}

// ---------- 2. barrier-free M=64 K-split GEMM, N-tile 128, direct-register ----------
// No LDS: each wave loads its own disjoint B rows + the shared A rows (L1 broadcast).
__global__ __launch_bounds__(256, 4) void k_gemm_nolds(
    const unsigned short* __restrict__ A1, const unsigned short* __restrict__ A2,
    const unsigned short* __restrict__ B1, const unsigned short* __restrict__ B2,
    float* __restrict__ C, int N, int nTiles, int n_split, int K, int Klen)
{
    const int tid = threadIdx.x;
    const int nb = blockIdx.x % nTiles;
    const int ks = blockIdx.x / nTiles;
    const int nBase = nb * 128;
    const bool use2 = nBase >= n_split;
    const unsigned short* A = use2 ? A2 : A1;
    const unsigned short* B = use2 ? B2 : B1;
    const int brow0 = nBase - (use2 ? n_split : 0);
    const int lane = tid & 63, w = tid >> 6;
    const int c = lane & 15, qd = lane >> 4;

    const unsigned short* ap[4];
    const unsigned short* bp[2];
#pragma unroll
    for (int i = 0; i < 4; ++i) ap[i] = A + (size_t)(i * 16 + c) * K + qd * 8;
#pragma unroll
    for (int j = 0; j < 2; ++j) bp[j] = B + (size_t)(brow0 + w * 32 + j * 16 + c) * K + qd * 8;

    const f32x4 fz = {0.f, 0.f, 0.f, 0.f};
    f32x4 acc[4][2];
#pragma unroll
    for (int i = 0; i < 4; ++i) { acc[i][0] = fz; acc[i][1] = fz; }

    const int k0b = ks * Klen;
    const int nkc = Klen >> 5;
#pragma unroll 2
    for (int kc = 0; kc < nkc; ++kc) {
        const int k0 = k0b + kc * 32;
        bf16x8 af[4], bf[2];
#pragma unroll
        for (int i = 0; i < 4; ++i) af[i] = *(const bf16x8*)(ap[i] + k0);
#pragma unroll
        for (int j = 0; j < 2; ++j) bf[j] = *(const bf16x8*)(bp[j] + k0);
#pragma unroll
        for (int j = 0; j < 2; ++j)
#pragma unroll
            for (int i = 0; i < 4; ++i) acc[i][j] = mfma16(af[i], bf[j], acc[i][j]);
    }
    float* Cp = C + (size_t)ks * 64 * N;
#pragma unroll
    for (int i = 0; i < 4; ++i)
#pragma unroll
        for (int r = 0; r < 4; ++r) {
            int row = i * 16 + qd * 4 + r;
#pragma unroll
            for (int j = 0; j < 2; ++j) {
                int col = nBase + w * 32 + j * 16 + c;
                Cp[row * N + col] = acc[i][j][r];
            }
        }
}

// ---------- 3. GRU gates (sums 4 K-split partials, adds biases) ----------
__global__ __launch_bounds__(256) void k_gates(
    const float* __restrict__ Cg, const float* __restrict__ h0,
    const float* __restrict__ bih, const float* __restrict__ bhh,
    float* __restrict__ outv, unsigned short* __restrict__ X3b)
{
    int idx = blockIdx.x * 256 + threadIdx.x;
    int b = idx >> 10, h = idx & 1023;
    float s[6];
#pragma unroll
    for (int g = 0; g < 6; ++g) s[g] = 0.f;
#pragma unroll
    for (int ks = 0; ks < 4; ++ks) {
        const float* g = Cg + ks * 393216 + b * 6144 + h;
#pragma unroll
        for (int k = 0; k < 6; ++k) s[k] += g[k * 1024];
    }
    float ir = s[0] + bih[h], iz = s[1] + bih[h + 1024], inn = s[2] + bih[h + 2048];
    float hr = s[3] + bhh[h], hz = s[4] + bhh[h + 1024], hn = s[5] + bhh[h + 2048];
    float r = 1.f / (1.f + __expf(-(ir + hr)));
    float z = 1.f / (1.f + __expf(-(iz + hz)));
    float n = tanh_fast(inn + r * hn);
    float o = (1.f - z) * n + z * h0[idx];
    outv[idx] = o;
    X3b[idx] = bf16_rne(o);
}

// ---------- 4. energy GEMM: 64M x 256N, barrier-free, A cvt-in-register ----------
// A = [annots fp32 | Lconv bf16] (K=544), B = Bbig[512][544] (L2-resident).
// No LDS in K-loop; 1-deep software prefetch; fused tanh + v-dot epilogue.
__global__ __launch_bounds__(256, 2) void k_attn(
    const float* __restrict__ annots, const unsigned short* __restrict__ Lconv,
    const unsigned short* __restrict__ Bbig, const float* __restrict__ pqP,
    const float* __restrict__ qb, const float* __restrict__ ebias,
    const float* __restrict__ vw, float* __restrict__ wsal)
{
    __shared__ float red[4][64];
    const int tid = threadIdx.x;
    const int mtile = blockIdx.x >> 1;
    const int split = blockIdx.x & 1;
    const int btBase = mtile * 64;
    const int b = mtile >> 4;
    const int nb2 = split * 256;
    const int lane = tid & 63, w = tid >> 6;
    const int c = lane & 15, qd = lane >> 4;

    const float* ap[4];
    const unsigned short* bp[4];
    const unsigned short* lp[4];
#pragma unroll
    for (int i = 0; i < 4; ++i) {
        ap[i] = annots + (size_t)(btBase + i * 16 + c) * 512 + qd * 8;
        lp[i] = Lconv + (size_t)(btBase + i * 16 + c) * 32 + qd * 8;
        bp[i] = Bbig + (size_t)(nb2 + w * 64 + i * 16 + c) * 544 + qd * 8;
    }

    const f32x4 fz = {0.f, 0.f, 0.f, 0.f};
    f32x4 acc[4][4];
#pragma unroll
    for (int i = 0; i < 4; ++i)
#pragma unroll
        for (int j = 0; j < 4; ++j) acc[i][j] = fz;

    // prefetch kc=0
    float4 ra0[4], ra1[4];
    uint4 rb[4];
#pragma unroll
    for (int i = 0; i < 4; ++i) {
        ra0[i] = *(const float4*)(ap[i]);
        ra1[i] = *(const float4*)(ap[i] + 4);
        rb[i] = *(const uint4*)(bp[i]);
    }
    uint4 rta[4];

#pragma unroll 5
    for (int kc = 0; kc < 15; ++kc) {
        bf16x8 af[4], bf[4];
#pragma unroll
        for (int i = 0; i < 4; ++i) { af[i] = cvt_bf(ra0[i], ra1[i]); bf[i] = as_bf(rb[i]); }
        const int k0 = (kc + 1) * 32;
#pragma unroll
        for (int i = 0; i < 4; ++i) {
            ra0[i] = *(const float4*)(ap[i] + k0);
            ra1[i] = *(const float4*)(ap[i] + k0 + 4);
            rb[i] = *(const uint4*)(bp[i] + k0);
        }
#pragma unroll
        for (int j = 0; j < 4; ++j)
#pragma unroll
            for (int i = 0; i < 4; ++i) acc[i][j] = mfma16(af[i], bf[j], acc[i][j]);
    }
    {   // kc = 15: compute, prefetch tail (Lconv + B cols 512..543)
        bf16x8 af[4], bf[4];
#pragma unroll
        for (int i = 0; i < 4; ++i) { af[i] = cvt_bf(ra0[i], ra1[i]); bf[i] = as_bf(rb[i]); }
#pragma unroll
        for (int i = 0; i < 4; ++i) {
            rta[i] = *(const uint4*)(lp[i]);
            rb[i] = *(const uint4*)(bp[i] + 512);
        }
#pragma unroll
        for (int j = 0; j < 4; ++j)
#pragma unroll
            for (int i = 0; i < 4; ++i) acc[i][j] = mfma16(af[i], bf[j], acc[i][j]);
    }
    {   // kc = 16: tail
        bf16x8 af[4], bf[4];
#pragma unroll
        for (int i = 0; i < 4; ++i) { af[i] = as_bf(rta[i]); bf[i] = as_bf(rb[i]); }
#pragma unroll
        for (int j = 0; j < 4; ++j)
#pragma unroll
            for (int i = 0; i < 4; ++i) acc[i][j] = mfma16(af[i], bf[j], acc[i][j]);
    }

    // epilogue: raw[t] += sum_col v[col]*tanh(acc + pq[b][col] + qb + ebias)
    float pe[4], vv[4];
#pragma unroll
    for (int j = 0; j < 4; ++j) {
        int colg = nb2 + w * 64 + j * 16 + c;
        float pq = qb[colg] + ebias[colg];
#pragma unroll
        for (int ks = 0; ks < 4; ++ks) pq += pqP[ks * 32768 + b * 512 + colg];
        pe[j] = pq;
        vv[j] = vw[colg];
    }
#pragma unroll
    for (int i = 0; i < 4; ++i)
#pragma unroll
        for (int r = 0; r < 4; ++r) {
            float p = 0.f;
#pragma unroll
            for (int j = 0; j < 4; ++j)
                p += vv[j] * tanh_fast(acc[i][j][r] + pe[j]);
            p += __shfl_xor(p, 1);
            p += __shfl_xor(p, 2);
            p += __shfl_xor(p, 4);
            p += __shfl_xor(p, 8);
            if (c == 0) red[w][i * 16 + qd * 4 + r] = p;
        }
    __syncthreads();
    if (tid < 64)
        wsal[split * 65536 + btBase + tid] = red[0][tid] + red[1][tid] + red[2][tid] + red[3][tid];
}

// ---------- 5. normalize + context, 1024-thread blocks (full occupancy) ----------
__global__ __launch_bounds__(1024) void k_ctx(
    const float* __restrict__ annots, const float* __restrict__ wsal,
    const int* __restrict__ mask, float* __restrict__ out)
{
    __shared__ float al[1024];
    __shared__ float wsum[16];
    __shared__ float red[16][64];
    const int b = blockIdx.x >> 3;
    const int chunk = blockIdx.x & 7;          // 64 cols each
    const int tid = threadIdx.x;
    const int bt = b * 1024 + tid;
    float raw = wsal[bt] + wsal[65536 + bt];
    float s = (mask[bt] != 0) ? 1.f / (1.f + __expf(-raw)) : 0.f;
    al[tid] = s;
    float ls = s;
    for (int off = 32; off > 0; off >>= 1) ls += __shfl_xor(ls, off);
    if ((tid & 63) == 0) wsum[tid >> 6] = ls;
    __syncthreads();
    float tot = 0.f;
#pragma unroll
    for (int i = 0; i < 16; ++i) tot += wsum[i];
    const float inv = 1.f / tot;
    if (chunk == 0) out[98304 + bt] = s * inv;

    const int dq = tid & 63, tq = tid >> 6;
    const float* ap = annots + (size_t)(b * 1024 + tq * 64) * 512 + chunk * 64 + dq;
    float acc = 0.f;
#pragma unroll 8
    for (int t = 0; t < 64; ++t) acc += al[tq * 64 + t] * ap[(size_t)t * 512];
    red[tq][dq] = acc;
    __syncthreads();
    if (tid < 64) {
        float s2 = 0.f;
#pragma unroll
        for (int i = 0; i < 16; ++i) s2 += red[i][tid];
        out[65536 + b * 512 + chunk * 64 + tid] = s2 * inv;
    }
}

extern "C" void kernel_launch(void* const* d_in, const int* in_sizes, int n_in,
                              void* d_out, int out_size, void* d_ws, size_t ws_size,
                              hipStream_t stream) {
    const float* memory    = (const float*)d_in[0];
    const float* context   = (const float*)d_in[1];
    const float* rnn_state = (const float*)d_in[2];
    const float* annots    = (const float*)d_in[3];
    const float* atten     = (const float*)d_in[4];
    const int*   mask      = (const int*)d_in[5];
    const float* W_ih   = (const float*)d_in[7];
    const float* W_hh   = (const float*)d_in[8];
    const float* b_ih   = (const float*)d_in[9];
    const float* b_hh   = (const float*)d_in[10];
    const float* conv_w = (const float*)d_in[11];
    const float* loc_w  = (const float*)d_in[12];
    const float* loc_b  = (const float*)d_in[13];
    const float* q_w    = (const float*)d_in[14];
    const float* q_b    = (const float*)d_in[15];
    const float* a_w    = (const float*)d_in[16];
    const float* a_b    = (const float*)d_in[17];
    const float* v_w    = (const float*)d_in[18];
    float* out = (float*)d_out;

    char* w8 = (char*)d_ws;
    unsigned short* Lconv = (unsigned short*)(w8 + 0);          //  4,194,304
    unsigned short* Bbig  = (unsigned short*)(w8 + 4194304);    //    557,056
    unsigned short* Wihb  = (unsigned short*)(w8 + 4751360);    //  6,291,456
    unsigned short* Whhb  = (unsigned short*)(w8 + 11042816);   //  6,291,456
    unsigned short* qwb   = (unsigned short*)(w8 + 17334272);   //  1,048,576
    unsigned short* X1b   = (unsigned short*)(w8 + 18382848);   //    131,072
    unsigned short* X2b   = (unsigned short*)(w8 + 18513920);   //    131,072
    unsigned short* X3b   = (unsigned short*)(w8 + 18644992);   //    131,072
    float*          Cgru  = (float*)(w8 + 18776064);            //  6,291,456 (4 partials)
    float*          pqP   = (float*)(w8 + 25067520);            //    524,288 (4 partials)
    float*          wsal  = (float*)(w8 + 25591808);            //    524,288 (2 partials)
    float*          ebias = (float*)(w8 + 26116096);            //      2,048

    k_prep<<<NB_CVT + 512, 256, 0, stream>>>(W_ih, W_hh, q_w, rnn_state, memory, context,
                                             a_w, loc_w, a_b, loc_b, atten, conv_w,
                                             Wihb, Whhb, qwb, X2b, X1b, Bbig, ebias, Lconv);
    // GRU: N=6144 (gi|gh), 48 N-tiles x K-split4 = 192 blocks, Klen=256
    k_gemm_nolds<<<192, 256, 0, stream>>>(X1b, X2b, Wihb, Whhb, Cgru, 6144, 48, 3072, 1024, 256);
    k_gates<<<256, 256, 0, stream>>>(Cgru, rnn_state, b_ih, b_hh, out, X3b);
    // pq: N=512, 4 N-tiles x K-split4 = 16 blocks, Klen=256
    k_gemm_nolds<<<16, 256, 0, stream>>>(X3b, X3b, qwb, qwb, pqP, 512, 4, 0x40000000, 1024, 256);
    k_attn<<<2048, 256, 0, stream>>>(annots, Lconv, Bbig, pqP, q_b, ebias, v_w, wsal);
    k_ctx<<<512, 1024, 0, stream>>>(annots, wsal, mask, out);
}

// Round 6
// 367.213 us; speedup vs baseline: 1.1566x; 1.1566x over previous
//
#include <hip/hip_runtime.h>

typedef float f32x4 __attribute__((ext_vector_type(4)));
typedef short bf16x8 __attribute__((ext_vector_type(8)));

// ---------- helpers ----------
__device__ __forceinline__ unsigned int pk2(float a, float b) {
    unsigned int ua = __float_as_uint(a); ua += 0x7FFFu + ((ua >> 16) & 1u);
    unsigned int ub = __float_as_uint(b); ub += 0x7FFFu + ((ub >> 16) & 1u);
    return __builtin_amdgcn_perm(ub, ua, 0x07060302u);
}
__device__ __forceinline__ unsigned short bf16_rne(float a) {
    unsigned int ua = __float_as_uint(a);
    ua += 0x7FFFu + ((ua >> 16) & 1u);
    return (unsigned short)(ua >> 16);
}
__device__ __forceinline__ float bf2f(unsigned int us) {
    return __uint_as_float(us << 16);
}
__device__ __forceinline__ float tanh_fast(float x) {
    float e = __expf(x + x);
    return 1.f - 2.f / (e + 1.f);
}
__device__ __forceinline__ f32x4 mfma16(bf16x8 a, bf16x8 b, f32x4 c) {
    return __builtin_amdgcn_mfma_f32_16x16x32_bf16(a, b, c, 0, 0, 0);
}
// async global->LDS DMA: per-lane global addr, LDS dest = wave-uniform base + lane*16
__device__ __forceinline__ void ald16(const void* g, void* l) {
    __builtin_amdgcn_global_load_lds(
        (const __attribute__((address_space(1))) unsigned int*)g,
        (__attribute__((address_space(3))) unsigned int*)l, 16, 0, 0);
}

// ---------- 1. prep: annots fp32->bf16 (8 octets/thread) + weights + location conv ----------
#define NB_ANN  2048             // 524,288 threads x 8 iters x 8 floats = 33,554,432 els
#define Q_WIH   786432
#define Q_WHH   1572864
#define Q_QW    1703936
#define Q_X2    1720320
#define Q_X1    1736704
#define Q_BAW   1802240
#define Q_BLW   1806336
#define Q_EB    1806464
#define NB_CVT  7057
#define NB_PREP (NB_ANN + NB_CVT + 512)

__global__ __launch_bounds__(256) void k_prep(
    const float* __restrict__ annots, unsigned short* __restrict__ annb,
    const float* __restrict__ Wih, const float* __restrict__ Whh,
    const float* __restrict__ qw, const float* __restrict__ rnn_state,
    const float* __restrict__ memory, const float* __restrict__ context,
    const float* __restrict__ aw, const float* __restrict__ lw,
    const float* __restrict__ ab, const float* __restrict__ lb,
    const float* __restrict__ atten, const float* __restrict__ convw,
    unsigned short* __restrict__ Wihb, unsigned short* __restrict__ Whhb,
    unsigned short* __restrict__ qwb, unsigned short* __restrict__ X2b,
    unsigned short* __restrict__ X1b, unsigned short* __restrict__ Bbig,
    float* __restrict__ ebias, unsigned short* __restrict__ Lconv)
{
    __shared__ float att_s[2 * 160];
    __shared__ float cw_s[1984];
    const int tid = threadIdx.x;
    if (blockIdx.x < NB_ANN) {
        const int t = blockIdx.x * 256 + tid;
#pragma unroll
        for (int it = 0; it < 8; ++it) {
            size_t i = ((size_t)it * 524288 + t) * 8;
            float4 v0 = *(const float4*)(annots + i);
            float4 v1 = *(const float4*)(annots + i + 4);
            uint4 u;
            u.x = pk2(v0.x, v0.y); u.y = pk2(v0.z, v0.w);
            u.z = pk2(v1.x, v1.y); u.w = pk2(v1.z, v1.w);
            *(uint4*)(annb + i) = u;
        }
    } else if (blockIdx.x < NB_ANN + NB_CVT) {
        int q = (blockIdx.x - NB_ANN) * 256 + tid;
        if (q >= Q_EB) return;
        if (q < Q_WIH) {
            int i = q * 4;
            float4 v = *(const float4*)(Wih + i);
            uint2 u; u.x = pk2(v.x, v.y); u.y = pk2(v.z, v.w);
            *(uint2*)(Wihb + i) = u;
        } else if (q < Q_WHH) {
            int i = (q - Q_WIH) * 4;
            float4 v = *(const float4*)(Whh + i);
            uint2 u; u.x = pk2(v.x, v.y); u.y = pk2(v.z, v.w);
            *(uint2*)(Whhb + i) = u;
        } else if (q < Q_QW) {
            int i = (q - Q_WHH) * 4;
            float4 v = *(const float4*)(qw + i);
            uint2 u; u.x = pk2(v.x, v.y); u.y = pk2(v.z, v.w);
            *(uint2*)(qwb + i) = u;
        } else if (q < Q_X2) {
            int i = (q - Q_QW) * 4;
            float4 v = *(const float4*)(rnn_state + i);
            uint2 u; u.x = pk2(v.x, v.y); u.y = pk2(v.z, v.w);
            *(uint2*)(X2b + i) = u;
        } else if (q < Q_X1) {
            int i = (q - Q_X2) * 4;
            int b = i >> 10, c = i & 1023;
            const float* s = (c < 512) ? (memory + b * 512 + c) : (context + b * 512 + (c - 512));
            float4 v = *(const float4*)s;
            uint2 u; u.x = pk2(v.x, v.y); u.y = pk2(v.z, v.w);
            *(uint2*)(X1b + i) = u;
        } else if (q < Q_BAW) {
            int i = (q - Q_X1) * 4;
            int a = i >> 9, c = i & 511;
            float4 v = *(const float4*)(aw + a * 512 + c);
            uint2 u; u.x = pk2(v.x, v.y); u.y = pk2(v.z, v.w);
            *(uint2*)(Bbig + a * 544 + c) = u;
        } else if (q < Q_BLW) {
            int i = (q - Q_BAW) * 4;
            int a = i >> 5, c = i & 31;
            float4 v = *(const float4*)(lw + a * 32 + c);
            uint2 u; u.x = pk2(v.x, v.y); u.y = pk2(v.z, v.w);
            *(uint2*)(Bbig + a * 544 + 512 + c) = u;
        } else {
            int i = (q - Q_BLW) * 4;
            float4 va = *(const float4*)(ab + i);
            float4 vb = *(const float4*)(lb + i);
            float4 r; r.x = va.x + vb.x; r.y = va.y + vb.y; r.z = va.z + vb.z; r.w = va.w + vb.w;
            *(float4*)(ebias + i) = r;
        }
    } else {
        const int bid = blockIdx.x - (NB_ANN + NB_CVT);
        const int b = bid >> 3;
        const int tbase = (bid & 7) * 128;
        for (int i = tid; i < 320; i += 256) {
            int c = i / 160, j = i % 160;
            float v = 0.f;
            int pos = tbase - 15 + j;
            if (j < 158 && pos >= 0 && pos < 1024) v = atten[b * 2048 + c * 1024 + pos];
            att_s[c * 160 + j] = v;
        }
        for (int i = tid; i < 1984; i += 256) cw_s[i] = convw[i];
        __syncthreads();
        const int f = tid & 31, tq = tid >> 5;
        float acc[16];
#pragma unroll
        for (int i = 0; i < 16; ++i) acc[i] = 0.f;
        for (int c = 0; c < 2; ++c) {
            for (int k = 0; k < 31; ++k) {
                float w = cw_s[f * 62 + c * 31 + k];
                int base = c * 160 + tq * 16 + k;
#pragma unroll
                for (int ti = 0; ti < 16; ++ti) acc[ti] += w * att_s[base + ti];
            }
        }
#pragma unroll
        for (int ti = 0; ti < 16; ++ti) {
            int t = tbase + tq * 16 + ti;
            Lconv[(b * 1024 + t) * 32 + f] = bf16_rne(acc[ti]);
        }
    }
}

// ---------- 2. M=64 K-split GEMM, N-tile 128: C[ks][64][N] partial = A @ B^T ----------
__global__ __launch_bounds__(256, 4) void k_gemm_ks(
    const unsigned short* __restrict__ A1, const unsigned short* __restrict__ A2,
    const unsigned short* __restrict__ B1, const unsigned short* __restrict__ B2,
    float* __restrict__ C, int N, int nTiles, int n_split, int K, int Klen)
{
    __shared__ __align__(16) unsigned short As[64 * 32];
    __shared__ __align__(16) unsigned short Bs[128 * 32];
    const int tid = threadIdx.x;
    const int nb = blockIdx.x % nTiles;
    const int ks = blockIdx.x / nTiles;
    const int nBase = nb * 128;
    const bool use2 = nBase >= n_split;
    const unsigned short* A = use2 ? A2 : A1;
    const unsigned short* B = use2 ? B2 : B1;
    const int brow0 = nBase - (use2 ? n_split : 0);
    const int lane = tid & 63, w = tid >> 6;
    const int c = lane & 15, qd = lane >> 4;
    const int lr = lane >> 2;
    const int swzl = ((lane & 3) ^ ((lr >> 1) & 3)) * 8;

    const f32x4 fz = {0.f, 0.f, 0.f, 0.f};
    f32x4 acc[4][2];
#pragma unroll
    for (int i = 0; i < 4; ++i) { acc[i][0] = fz; acc[i][1] = fz; }

    const int k0b = ks * Klen;
    const int nkc = Klen >> 5;
    for (int kc = 0; kc < nkc; ++kc) {
        const int k0 = k0b + kc * 32;
        ald16(A + (size_t)(w * 16 + lr) * K + k0 + swzl, &As[w * 512]);
        ald16(B + (size_t)(brow0 + w * 16 + lr) * K + k0 + swzl, &Bs[w * 512]);
        ald16(B + (size_t)(brow0 + 64 + w * 16 + lr) * K + k0 + swzl, &Bs[2048 + w * 512]);
        __syncthreads();
        const int rdoff = (qd ^ ((c >> 1) & 3)) * 8;
        bf16x8 af[4];
#pragma unroll
        for (int i = 0; i < 4; ++i) af[i] = *(const bf16x8*)&As[(i * 16 + c) * 32 + rdoff];
#pragma unroll
        for (int j = 0; j < 2; ++j) {
            bf16x8 bj = *(const bf16x8*)&Bs[(w * 32 + j * 16 + c) * 32 + rdoff];
#pragma unroll
            for (int i = 0; i < 4; ++i) acc[i][j] = mfma16(af[i], bj, acc[i][j]);
        }
        __syncthreads();
    }
    float* Cp = C + (size_t)ks * 64 * N;
#pragma unroll
    for (int i = 0; i < 4; ++i)
#pragma unroll
        for (int r = 0; r < 4; ++r) {
            int row = i * 16 + qd * 4 + r;
#pragma unroll
            for (int j = 0; j < 2; ++j) {
                int col = nBase + w * 32 + j * 16 + c;
                Cp[row * N + col] = acc[i][j][r];
            }
        }
}

// ---------- 3. GRU gates (sums 4 K-split partials, adds biases) ----------
__global__ __launch_bounds__(256) void k_gates(
    const float* __restrict__ Cg, const float* __restrict__ h0,
    const float* __restrict__ bih, const float* __restrict__ bhh,
    float* __restrict__ outv, unsigned short* __restrict__ X3b)
{
    int idx = blockIdx.x * 256 + threadIdx.x;
    int b = idx >> 10, h = idx & 1023;
    float s[6];
#pragma unroll
    for (int g = 0; g < 6; ++g) s[g] = 0.f;
#pragma unroll
    for (int ks = 0; ks < 4; ++ks) {
        const float* g = Cg + ks * 393216 + b * 6144 + h;
#pragma unroll
        for (int k = 0; k < 6; ++k) s[k] += g[k * 1024];
    }
    float ir = s[0] + bih[h], iz = s[1] + bih[h + 1024], inn = s[2] + bih[h + 2048];
    float hr = s[3] + bhh[h], hz = s[4] + bhh[h + 1024], hn = s[5] + bhh[h + 2048];
    float r = 1.f / (1.f + __expf(-(ir + hr)));
    float z = 1.f / (1.f + __expf(-(iz + hz)));
    float n = tanh_fast(inn + r * hn);
    float o = (1.f - z) * n + z * h0[idx];
    outv[idx] = o;
    X3b[idx] = bf16_rne(o);
}

// ---------- 4. energy GEMM: 64M x 256N tiles, all-DMA staging, fused tanh/v-dot ----------
// A = [annb | Lconv] (K=544), B = Bbig[512][544]. grid: mtile-major x 2 N-splits.
__global__ __launch_bounds__(256, 4) void k_attn(
    const unsigned short* __restrict__ annb, const unsigned short* __restrict__ Lconv,
    const unsigned short* __restrict__ Bbig, const float* __restrict__ pqP,
    const float* __restrict__ qb, const float* __restrict__ ebias,
    const float* __restrict__ vw, float* __restrict__ wsal)
{
    __shared__ __align__(16) unsigned short As[64 * 32];    //  4 KB
    __shared__ __align__(16) unsigned short Bs[256 * 32];   // 16 KB
    __shared__ float red[4][64];                            //  1 KB
    const int tid = threadIdx.x;
    const int mtile = blockIdx.x >> 1;
    const int split = blockIdx.x & 1;
    const int btBase = mtile * 64;
    const int b = mtile >> 4;
    const int nb2 = split * 256;
    const int lane = tid & 63, w = tid >> 6;
    const int c = lane & 15, qd = lane >> 4;
    const int lr = lane >> 2;
    const int swzl = ((lane & 3) ^ ((lr >> 1) & 3)) * 8;

    const f32x4 fz = {0.f, 0.f, 0.f, 0.f};
    f32x4 acc[4][4];
#pragma unroll
    for (int i = 0; i < 4; ++i)
#pragma unroll
        for (int j = 0; j < 4; ++j) acc[i][j] = fz;

    const int arow = btBase + w * 16 + lr;       // A row this lane stages
    for (int kc = 0; kc < 17; ++kc) {
        const int k0 = kc * 32;
        // A: 64 rows x 32k; 4 wave-issues (1 per wave)
        if (kc < 16)
            ald16(annb + (size_t)arow * 512 + k0 + swzl, &As[w * 512]);
        else
            ald16(Lconv + (size_t)arow * 32 + swzl, &As[w * 512]);
        // B: 256 rows x 32k; 16 issues (4 per wave); k0=512 works for kc==16 (cols 512..543)
#pragma unroll
        for (int s = 0; s < 4; ++s)
            ald16(Bbig + (size_t)(nb2 + s * 64 + w * 16 + lr) * 544 + k0 + swzl,
                  &Bs[s * 2048 + w * 512]);
        __syncthreads();
        const int rdoff = (qd ^ ((c >> 1) & 3)) * 8;
        bf16x8 af[4];
#pragma unroll
        for (int i = 0; i < 4; ++i) af[i] = *(const bf16x8*)&As[(i * 16 + c) * 32 + rdoff];
#pragma unroll
        for (int j = 0; j < 4; ++j) {
            bf16x8 bj = *(const bf16x8*)&Bs[(w * 64 + j * 16 + c) * 32 + rdoff];
#pragma unroll
            for (int i = 0; i < 4; ++i) acc[i][j] = mfma16(af[i], bj, acc[i][j]);
        }
        __syncthreads();
    }
    // epilogue: raw[t] += sum_col v[col]*tanh(acc + pq[b][col] + qb + ebias)
    float pe[4], vv[4];
#pragma unroll
    for (int j = 0; j < 4; ++j) {
        int colg = nb2 + w * 64 + j * 16 + c;
        float pq = qb[colg] + ebias[colg];
#pragma unroll
        for (int ks = 0; ks < 4; ++ks) pq += pqP[ks * 32768 + b * 512 + colg];
        pe[j] = pq;
        vv[j] = vw[colg];
    }
#pragma unroll
    for (int i = 0; i < 4; ++i)
#pragma unroll
        for (int r = 0; r < 4; ++r) {
            float p = 0.f;
#pragma unroll
            for (int j = 0; j < 4; ++j)
                p += vv[j] * tanh_fast(acc[i][j][r] + pe[j]);
            p += __shfl_xor(p, 1);
            p += __shfl_xor(p, 2);
            p += __shfl_xor(p, 4);
            p += __shfl_xor(p, 8);
            if (c == 0) red[w][i * 16 + qd * 4 + r] = p;
        }
    __syncthreads();
    if (tid < 64)
        wsal[split * 65536 + btBase + tid] = red[0][tid] + red[1][tid] + red[2][tid] + red[3][tid];
}

// ---------- 5. normalize + context (bf16 annots) ----------
__global__ __launch_bounds__(256) void k_ctx(
    const unsigned short* __restrict__ annb, const float* __restrict__ wsal,
    const int* __restrict__ mask, float* __restrict__ out)
{
    __shared__ float al[1024];
    __shared__ float wsum[4];
    __shared__ float2 red[256];
    const int b = blockIdx.x >> 2;
    const int chunk = blockIdx.x & 3;          // 128 cols each
    const int tid = threadIdx.x;
    float lsum = 0.f;
#pragma unroll
    for (int p = 0; p < 4; ++p) {
        int t = p * 256 + tid;
        int bt = b * 1024 + t;
        float raw = wsal[bt] + wsal[65536 + bt];
        float s = (mask[bt] != 0) ? 1.f / (1.f + __expf(-raw)) : 0.f;
        al[t] = s;
        lsum += s;
    }
    for (int off = 32; off > 0; off >>= 1) lsum += __shfl_xor(lsum, off);
    if ((tid & 63) == 0) wsum[tid >> 6] = lsum;
    __syncthreads();
    const float tot = wsum[0] + wsum[1] + wsum[2] + wsum[3];
    const float inv = 1.f / tot;
    if (chunk == 0) {
#pragma unroll
        for (int p = 0; p < 4; ++p) {
            int t = p * 256 + tid;
            out[98304 + b * 1024 + t] = al[t] * inv;
        }
    }
    // context: 2 cols per thread, t-quartered
    const int dq = tid & 63, tq = tid >> 6;
    const int d0 = chunk * 128 + dq * 2;
    const unsigned short* ap = annb + (size_t)(b * 1024 + tq * 256) * 512 + d0;
    float a0 = 0.f, a1 = 0.f;
#pragma unroll 4
    for (int t = 0; t < 256; ++t) {
        unsigned int u = *(const unsigned int*)(ap + (size_t)t * 512);
        float wgt = al[tq * 256 + t];
        a0 += wgt * bf2f(u & 0xFFFFu);
        a1 += wgt * bf2f(u >> 16);
    }
    red[tid].x = a0; red[tid].y = a1;
    __syncthreads();
    if (tid < 64) {
        float2 s2;
        s2.x = red[tid].x + red[64 + tid].x + red[128 + tid].x + red[192 + tid].x;
        s2.y = red[tid].y + red[64 + tid].y + red[128 + tid].y + red[192 + tid].y;
        float2 o; o.x = s2.x * inv; o.y = s2.y * inv;
        *(float2*)(out + 65536 + b * 512 + chunk * 128 + tid * 2) = o;
    }
}

extern "C" void kernel_launch(void* const* d_in, const int* in_sizes, int n_in,
                              void* d_out, int out_size, void* d_ws, size_t ws_size,
                              hipStream_t stream) {
    const float* memory    = (const float*)d_in[0];
    const float* context   = (const float*)d_in[1];
    const float* rnn_state = (const float*)d_in[2];
    const float* annots    = (const float*)d_in[3];
    const float* atten     = (const float*)d_in[4];
    const int*   mask      = (const int*)d_in[5];
    const float* W_ih   = (const float*)d_in[7];
    const float* W_hh   = (const float*)d_in[8];
    const float* b_ih   = (const float*)d_in[9];
    const float* b_hh   = (const float*)d_in[10];
    const float* conv_w = (const float*)d_in[11];
    const float* loc_w  = (const float*)d_in[12];
    const float* loc_b  = (const float*)d_in[13];
    const float* q_w    = (const float*)d_in[14];
    const float* q_b    = (const float*)d_in[15];
    const float* a_w    = (const float*)d_in[16];
    const float* a_b    = (const float*)d_in[17];
    const float* v_w    = (const float*)d_in[18];
    float* out = (float*)d_out;

    char* w8 = (char*)d_ws;
    unsigned short* Lconv = (unsigned short*)(w8 + 0);          //  4,194,304
    unsigned short* Bbig  = (unsigned short*)(w8 + 4194304);    //    557,056
    unsigned short* annb  = (unsigned short*)(w8 + 4751360);    // 67,108,864
    unsigned short* Wihb  = (unsigned short*)(w8 + 71860224);   //  6,291,456
    unsigned short* Whhb  = (unsigned short*)(w8 + 78151680);   //  6,291,456
    unsigned short* qwb   = (unsigned short*)(w8 + 84443136);   //  1,048,576
    unsigned short* X1b   = (unsigned short*)(w8 + 85491712);   //    131,072
    unsigned short* X2b   = (unsigned short*)(w8 + 85622784);   //    131,072
    unsigned short* X3b   = (unsigned short*)(w8 + 85753856);   //    131,072
    float*          Cgru  = (float*)(w8 + 85884928);            //  6,291,456 (4 partials)
    float*          pqP   = (float*)(w8 + 92176384);            //    524,288 (4 partials)
    float*          wsal  = (float*)(w8 + 92700672);            //    524,288 (2 partials)
    float*          ebias = (float*)(w8 + 93224960);            //      2,048

    k_prep<<<NB_PREP, 256, 0, stream>>>(annots, annb,
                                        W_ih, W_hh, q_w, rnn_state, memory, context,
                                        a_w, loc_w, a_b, loc_b, atten, conv_w,
                                        Wihb, Whhb, qwb, X2b, X1b, Bbig, ebias, Lconv);
    // GRU: N=6144 (gi|gh), 48 N-tiles x K-split4 = 192 blocks, Klen=256
    k_gemm_ks<<<192, 256, 0, stream>>>(X1b, X2b, Wihb, Whhb, Cgru, 6144, 48, 3072, 1024, 256);
    k_gates<<<256, 256, 0, stream>>>(Cgru, rnn_state, b_ih, b_hh, out, X3b);
    // pq: N=512, 4 N-tiles x K-split4 = 16 blocks, Klen=256
    k_gemm_ks<<<16, 256, 0, stream>>>(X3b, X3b, qwb, qwb, pqP, 512, 4, 0x40000000, 1024, 256);
    k_attn<<<2048, 256, 0, stream>>>(annb, Lconv, Bbig, pqP, q_b, ebias, v_w, wsal);
    k_ctx<<<256, 256, 0, stream>>>(annb, wsal, mask, out);
}

// Round 7
// 352.963 us; speedup vs baseline: 1.2033x; 1.0404x over previous
//
#include <hip/hip_runtime.h>

typedef float f32x4 __attribute__((ext_vector_type(4)));
typedef short bf16x8 __attribute__((ext_vector_type(8)));

// ---------- helpers ----------
__device__ __forceinline__ unsigned int pk2(float a, float b) {
    unsigned int ua = __float_as_uint(a); ua += 0x7FFFu + ((ua >> 16) & 1u);
    unsigned int ub = __float_as_uint(b); ub += 0x7FFFu + ((ub >> 16) & 1u);
    return __builtin_amdgcn_perm(ub, ua, 0x07060302u);
}
__device__ __forceinline__ unsigned short bf16_rne(float a) {
    unsigned int ua = __float_as_uint(a);
    ua += 0x7FFFu + ((ua >> 16) & 1u);
    return (unsigned short)(ua >> 16);
}
__device__ __forceinline__ float tanh_fast(float x) {
    float e = __expf(x + x);
    return 1.f - 2.f / (e + 1.f);
}
__device__ __forceinline__ f32x4 mfma16(bf16x8 a, bf16x8 b, f32x4 c) {
    return __builtin_amdgcn_mfma_f32_16x16x32_bf16(a, b, c, 0, 0, 0);
}
// async global->LDS DMA: per-lane global addr, LDS dest = wave-uniform base + lane*16
__device__ __forceinline__ void ald16(const void* g, void* l) {
    __builtin_amdgcn_global_load_lds(
        (const __attribute__((address_space(1))) unsigned int*)g,
        (__attribute__((address_space(3))) unsigned int*)l, 16, 0, 0);
}

// ---------- 1. prep: weight conversion + location conv (no annots pass) ----------
#define Q_WIH   786432
#define Q_WHH   1572864
#define Q_QW    1703936
#define Q_X2    1720320
#define Q_X1    1736704
#define Q_BAW   1802240
#define Q_BLW   1806336
#define Q_EB    1806464
#define NB_CVT  7057

__global__ __launch_bounds__(256) void k_prep(
    const float* __restrict__ Wih, const float* __restrict__ Whh,
    const float* __restrict__ qw, const float* __restrict__ rnn_state,
    const float* __restrict__ memory, const float* __restrict__ context,
    const float* __restrict__ aw, const float* __restrict__ lw,
    const float* __restrict__ ab, const float* __restrict__ lb,
    const float* __restrict__ atten, const float* __restrict__ convw,
    unsigned short* __restrict__ Wihb, unsigned short* __restrict__ Whhb,
    unsigned short* __restrict__ qwb, unsigned short* __restrict__ X2b,
    unsigned short* __restrict__ X1b, unsigned short* __restrict__ Bbig,
    float* __restrict__ ebias, unsigned short* __restrict__ Lconv)
{
    __shared__ float att_s[2 * 160];
    __shared__ float cw_s[1984];
    const int tid = threadIdx.x;
    if (blockIdx.x < NB_CVT) {
        int q = blockIdx.x * 256 + tid;
        if (q >= Q_EB) return;
        if (q < Q_WIH) {
            int i = q * 4;
            float4 v = *(const float4*)(Wih + i);
            uint2 u; u.x = pk2(v.x, v.y); u.y = pk2(v.z, v.w);
            *(uint2*)(Wihb + i) = u;
        } else if (q < Q_WHH) {
            int i = (q - Q_WIH) * 4;
            float4 v = *(const float4*)(Whh + i);
            uint2 u; u.x = pk2(v.x, v.y); u.y = pk2(v.z, v.w);
            *(uint2*)(Whhb + i) = u;
        } else if (q < Q_QW) {
            int i = (q - Q_WHH) * 4;
            float4 v = *(const float4*)(qw + i);
            uint2 u; u.x = pk2(v.x, v.y); u.y = pk2(v.z, v.w);
            *(uint2*)(qwb + i) = u;
        } else if (q < Q_X2) {
            int i = (q - Q_QW) * 4;
            float4 v = *(const float4*)(rnn_state + i);
            uint2 u; u.x = pk2(v.x, v.y); u.y = pk2(v.z, v.w);
            *(uint2*)(X2b + i) = u;
        } else if (q < Q_X1) {
            int i = (q - Q_X2) * 4;
            int b = i >> 10, c = i & 1023;
            const float* s = (c < 512) ? (memory + b * 512 + c) : (context + b * 512 + (c - 512));
            float4 v = *(const float4*)s;
            uint2 u; u.x = pk2(v.x, v.y); u.y = pk2(v.z, v.w);
            *(uint2*)(X1b + i) = u;
        } else if (q < Q_BAW) {
            int i = (q - Q_X1) * 4;
            int a = i >> 9, c = i & 511;
            float4 v = *(const float4*)(aw + a * 512 + c);
            uint2 u; u.x = pk2(v.x, v.y); u.y = pk2(v.z, v.w);
            *(uint2*)(Bbig + a * 544 + c) = u;
        } else if (q < Q_BLW) {
            int i = (q - Q_BAW) * 4;
            int a = i >> 5, c = i & 31;
            float4 v = *(const float4*)(lw + a * 32 + c);
            uint2 u; u.x = pk2(v.x, v.y); u.y = pk2(v.z, v.w);
            *(uint2*)(Bbig + a * 544 + 512 + c) = u;
        } else {
            int i = (q - Q_BLW) * 4;
            float4 va = *(const float4*)(ab + i);
            float4 vb = *(const float4*)(lb + i);
            float4 r; r.x = va.x + vb.x; r.y = va.y + vb.y; r.z = va.z + vb.z; r.w = va.w + vb.w;
            *(float4*)(ebias + i) = r;
        }
    } else {
        const int bid = blockIdx.x - NB_CVT;
        const int b = bid >> 3;
        const int tbase = (bid & 7) * 128;
        for (int i = tid; i < 320; i += 256) {
            int c = i / 160, j = i % 160;
            float v = 0.f;
            int pos = tbase - 15 + j;
            if (j < 158 && pos >= 0 && pos < 1024) v = atten[b * 2048 + c * 1024 + pos];
            att_s[c * 160 + j] = v;
        }
        for (int i = tid; i < 1984; i += 256) cw_s[i] = convw[i];
        __syncthreads();
        const int f = tid & 31, tq = tid >> 5;
        float acc[16];
#pragma unroll
        for (int i = 0; i < 16; ++i) acc[i] = 0.f;
        for (int c = 0; c < 2; ++c) {
            for (int k = 0; k < 31; ++k) {
                float w = cw_s[f * 62 + c * 31 + k];
                int base = c * 160 + tq * 16 + k;
#pragma unroll
                for (int ti = 0; ti < 16; ++ti) acc[ti] += w * att_s[base + ti];
            }
        }
#pragma unroll
        for (int ti = 0; ti < 16; ++ti) {
            int t = tbase + tq * 16 + ti;
            Lconv[(b * 1024 + t) * 32 + f] = bf16_rne(acc[ti]);
        }
    }
}

// ---------- 2. M=64 K-split GEMM, N-tile 128: C[ks][64][N] partial = A @ B^T ----------
__global__ __launch_bounds__(256, 4) void k_gemm_ks(
    const unsigned short* __restrict__ A1, const unsigned short* __restrict__ A2,
    const unsigned short* __restrict__ B1, const unsigned short* __restrict__ B2,
    float* __restrict__ C, int N, int nTiles, int n_split, int K, int Klen)
{
    __shared__ __align__(16) unsigned short As[64 * 32];
    __shared__ __align__(16) unsigned short Bs[128 * 32];
    const int tid = threadIdx.x;
    const int nb = blockIdx.x % nTiles;
    const int ks = blockIdx.x / nTiles;
    const int nBase = nb * 128;
    const bool use2 = nBase >= n_split;
    const unsigned short* A = use2 ? A2 : A1;
    const unsigned short* B = use2 ? B2 : B1;
    const int brow0 = nBase - (use2 ? n_split : 0);
    const int lane = tid & 63, w = tid >> 6;
    const int c = lane & 15, qd = lane >> 4;
    const int lr = lane >> 2;
    const int swzl = ((lane & 3) ^ ((lr >> 1) & 3)) * 8;

    const f32x4 fz = {0.f, 0.f, 0.f, 0.f};
    f32x4 acc[4][2];
#pragma unroll
    for (int i = 0; i < 4; ++i) { acc[i][0] = fz; acc[i][1] = fz; }

    const int k0b = ks * Klen;
    const int nkc = Klen >> 5;
    for (int kc = 0; kc < nkc; ++kc) {
        const int k0 = k0b + kc * 32;
        ald16(A + (size_t)(w * 16 + lr) * K + k0 + swzl, &As[w * 512]);
        ald16(B + (size_t)(brow0 + w * 16 + lr) * K + k0 + swzl, &Bs[w * 512]);
        ald16(B + (size_t)(brow0 + 64 + w * 16 + lr) * K + k0 + swzl, &Bs[2048 + w * 512]);
        __syncthreads();
        const int rdoff = (qd ^ ((c >> 1) & 3)) * 8;
        bf16x8 af[4];
#pragma unroll
        for (int i = 0; i < 4; ++i) af[i] = *(const bf16x8*)&As[(i * 16 + c) * 32 + rdoff];
#pragma unroll
        for (int j = 0; j < 2; ++j) {
            bf16x8 bj = *(const bf16x8*)&Bs[(w * 32 + j * 16 + c) * 32 + rdoff];
#pragma unroll
            for (int i = 0; i < 4; ++i) acc[i][j] = mfma16(af[i], bj, acc[i][j]);
        }
        __syncthreads();
    }
    float* Cp = C + (size_t)ks * 64 * N;
#pragma unroll
    for (int i = 0; i < 4; ++i)
#pragma unroll
        for (int r = 0; r < 4; ++r) {
            int row = i * 16 + qd * 4 + r;
#pragma unroll
            for (int j = 0; j < 2; ++j) {
                int col = nBase + w * 32 + j * 16 + c;
                Cp[row * N + col] = acc[i][j][r];
            }
        }
}

// ---------- 3. GRU gates (sums 4 K-split partials, adds biases) ----------
__global__ __launch_bounds__(256) void k_gates(
    const float* __restrict__ Cg, const float* __restrict__ h0,
    const float* __restrict__ bih, const float* __restrict__ bhh,
    float* __restrict__ outv, unsigned short* __restrict__ X3b)
{
    int idx = blockIdx.x * 256 + threadIdx.x;
    int b = idx >> 10, h = idx & 1023;
    float s[6];
#pragma unroll
    for (int g = 0; g < 6; ++g) s[g] = 0.f;
#pragma unroll
    for (int ks = 0; ks < 4; ++ks) {
        const float* g = Cg + ks * 393216 + b * 6144 + h;
#pragma unroll
        for (int k = 0; k < 6; ++k) s[k] += g[k * 1024];
    }
    float ir = s[0] + bih[h], iz = s[1] + bih[h + 1024], inn = s[2] + bih[h + 2048];
    float hr = s[3] + bhh[h], hz = s[4] + bhh[h + 1024], hn = s[5] + bhh[h + 2048];
    float r = 1.f / (1.f + __expf(-(ir + hr)));
    float z = 1.f / (1.f + __expf(-(iz + hz)));
    float n = tanh_fast(inn + r * hn);
    float o = (1.f - z) * n + z * h0[idx];
    outv[idx] = o;
    X3b[idx] = bf16_rne(o);
}

// ---------- 4. energy GEMM: 64M x 256N, A = fp32 annots cvt-in-staging, B via DMA ----------
// A = [annots fp32 -> bf16 inline | Lconv] (K=544), B = Bbig[512][544] (L2-resident).
__global__ __launch_bounds__(256, 4) void k_attn(
    const float* __restrict__ annots, const unsigned short* __restrict__ Lconv,
    const unsigned short* __restrict__ Bbig, const float* __restrict__ pqP,
    const float* __restrict__ qb, const float* __restrict__ ebias,
    const float* __restrict__ vw, float* __restrict__ wsal)
{
    __shared__ __align__(16) unsigned short As[64 * 32];    //  4 KB
    __shared__ __align__(16) unsigned short Bs[256 * 32];   // 16 KB
    __shared__ float red[4][64];                            //  1 KB
    const int tid = threadIdx.x;
    const int mtile = blockIdx.x >> 1;
    const int split = blockIdx.x & 1;
    const int btBase = mtile * 64;
    const int b = mtile >> 4;
    const int nb2 = split * 256;
    const int lane = tid & 63, w = tid >> 6;
    const int c = lane & 15, qd = lane >> 4;
    const int lr = lane >> 2;
    const int swzl = ((lane & 3) ^ ((lr >> 1) & 3)) * 8;
    const int arow = tid >> 2, alc = tid & 3;
    const int apofs = (alc ^ ((arow >> 1) & 3)) * 8;

    const f32x4 fz = {0.f, 0.f, 0.f, 0.f};
    f32x4 acc[4][4];
#pragma unroll
    for (int i = 0; i < 4; ++i)
#pragma unroll
        for (int j = 0; j < 4; ++j) acc[i][j] = fz;

    for (int kc = 0; kc < 17; ++kc) {
        const int k0 = kc * 32;
        // B: 256 rows x 32k; 4 DMA issues per wave; k0=512 covers kc==16 (cols 512..543)
#pragma unroll
        for (int s = 0; s < 4; ++s)
            ald16(Bbig + (size_t)(nb2 + s * 64 + w * 16 + lr) * 544 + k0 + swzl,
                  &Bs[s * 2048 + w * 512]);
        if (kc < 16) {
            // A: 64 rows x 32k fp32 -> bf16 inline (proven R2 staging)
            const float* p = annots + (size_t)(btBase + arow) * 512 + k0 + alc * 8;
            float4 v0 = *(const float4*)p;
            float4 v1 = *(const float4*)(p + 4);
            uint4 u;
            u.x = pk2(v0.x, v0.y); u.y = pk2(v0.z, v0.w);
            u.z = pk2(v1.x, v1.y); u.w = pk2(v1.z, v1.w);
            *(uint4*)&As[arow * 32 + apofs] = u;
        } else {
            ald16(Lconv + (size_t)(btBase + w * 16 + lr) * 32 + swzl, &As[w * 512]);
        }
        __syncthreads();
        const int rdoff = (qd ^ ((c >> 1) & 3)) * 8;
        bf16x8 af[4];
#pragma unroll
        for (int i = 0; i < 4; ++i) af[i] = *(const bf16x8*)&As[(i * 16 + c) * 32 + rdoff];
#pragma unroll
        for (int j = 0; j < 4; ++j) {
            bf16x8 bj = *(const bf16x8*)&Bs[(w * 64 + j * 16 + c) * 32 + rdoff];
#pragma unroll
            for (int i = 0; i < 4; ++i) acc[i][j] = mfma16(af[i], bj, acc[i][j]);
        }
        __syncthreads();
    }
    // epilogue: raw[t] += sum_col v[col]*tanh(acc + pq[b][col] + qb + ebias)
    float pe[4], vv[4];
#pragma unroll
    for (int j = 0; j < 4; ++j) {
        int colg = nb2 + w * 64 + j * 16 + c;
        float pq = qb[colg] + ebias[colg];
#pragma unroll
        for (int ks = 0; ks < 4; ++ks) pq += pqP[ks * 32768 + b * 512 + colg];
        pe[j] = pq;
        vv[j] = vw[colg];
    }
#pragma unroll
    for (int i = 0; i < 4; ++i)
#pragma unroll
        for (int r = 0; r < 4; ++r) {
            float p = 0.f;
#pragma unroll
            for (int j = 0; j < 4; ++j)
                p += vv[j] * tanh_fast(acc[i][j][r] + pe[j]);
            p += __shfl_xor(p, 1);
            p += __shfl_xor(p, 2);
            p += __shfl_xor(p, 4);
            p += __shfl_xor(p, 8);
            if (c == 0) red[w][i * 16 + qd * 4 + r] = p;
        }
    __syncthreads();
    if (tid < 64)
        wsal[split * 65536 + btBase + tid] = red[0][tid] + red[1][tid] + red[2][tid] + red[3][tid];
}

// ---------- 5. normalize + context (fp32 annots, proven R2 form) ----------
__global__ __launch_bounds__(256) void k_ctx(
    const float* __restrict__ annots, const float* __restrict__ wsal,
    const int* __restrict__ mask, float* __restrict__ out)
{
    __shared__ float al[1024];
    __shared__ float wsum[4];
    __shared__ float red[256];
    const int b = blockIdx.x >> 3;
    const int chunk = blockIdx.x & 7;
    const int tid = threadIdx.x;
    float lsum = 0.f;
#pragma unroll
    for (int p = 0; p < 4; ++p) {
        int t = p * 256 + tid;
        int bt = b * 1024 + t;
        float raw = wsal[bt] + wsal[65536 + bt];
        float s = (mask[bt] != 0) ? 1.f / (1.f + __expf(-raw)) : 0.f;
        al[t] = s;
        lsum += s;
    }
    for (int off = 32; off > 0; off >>= 1) lsum += __shfl_xor(lsum, off);
    if ((tid & 63) == 0) wsum[tid >> 6] = lsum;
    __syncthreads();
    const float tot = wsum[0] + wsum[1] + wsum[2] + wsum[3];
    const float inv = 1.f / tot;
    if (chunk == 0) {
#pragma unroll
        for (int p = 0; p < 4; ++p) {
            int t = p * 256 + tid;
            out[98304 + b * 1024 + t] = al[t] * inv;
        }
    }
    const int dq = tid & 63, tq = tid >> 6;
    const int d = chunk * 64 + dq;
    const float* ap = annots + (size_t)(b * 1024 + tq * 256) * 512 + d;
    float acc = 0.f;
#pragma unroll 4
    for (int t = 0; t < 256; ++t) acc += al[tq * 256 + t] * ap[(size_t)t * 512];
    red[tid] = acc;
    __syncthreads();
    if (tid < 64) {
        float s2 = red[tid] + red[64 + tid] + red[128 + tid] + red[192 + tid];
        out[65536 + b * 512 + chunk * 64 + tid] = s2 * inv;
    }
}

extern "C" void kernel_launch(void* const* d_in, const int* in_sizes, int n_in,
                              void* d_out, int out_size, void* d_ws, size_t ws_size,
                              hipStream_t stream) {
    const float* memory    = (const float*)d_in[0];
    const float* context   = (const float*)d_in[1];
    const float* rnn_state = (const float*)d_in[2];
    const float* annots    = (const float*)d_in[3];
    const float* atten     = (const float*)d_in[4];
    const int*   mask      = (const int*)d_in[5];
    const float* W_ih   = (const float*)d_in[7];
    const float* W_hh   = (const float*)d_in[8];
    const float* b_ih   = (const float*)d_in[9];
    const float* b_hh   = (const float*)d_in[10];
    const float* conv_w = (const float*)d_in[11];
    const float* loc_w  = (const float*)d_in[12];
    const float* loc_b  = (const float*)d_in[13];
    const float* q_w    = (const float*)d_in[14];
    const float* q_b    = (const float*)d_in[15];
    const float* a_w    = (const float*)d_in[16];
    const float* a_b    = (const float*)d_in[17];
    const float* v_w    = (const float*)d_in[18];
    float* out = (float*)d_out;

    char* w8 = (char*)d_ws;
    unsigned short* Lconv = (unsigned short*)(w8 + 0);          //  4,194,304
    unsigned short* Bbig  = (unsigned short*)(w8 + 4194304);    //    557,056
    unsigned short* Wihb  = (unsigned short*)(w8 + 4751360);    //  6,291,456
    unsigned short* Whhb  = (unsigned short*)(w8 + 11042816);   //  6,291,456
    unsigned short* qwb   = (unsigned short*)(w8 + 17334272);   //  1,048,576
    unsigned short* X1b   = (unsigned short*)(w8 + 18382848);   //    131,072
    unsigned short* X2b   = (unsigned short*)(w8 + 18513920);   //    131,072
    unsigned short* X3b   = (unsigned short*)(w8 + 18644992);   //    131,072
    float*          Cgru  = (float*)(w8 + 18776064);            //  6,291,456 (4 partials)
    float*          pqP   = (float*)(w8 + 25067520);            //    524,288 (4 partials)
    float*          wsal  = (float*)(w8 + 25591808);            //    524,288 (2 partials)
    float*          ebias = (float*)(w8 + 26116096);            //      2,048

    k_prep<<<NB_CVT + 512, 256, 0, stream>>>(W_ih, W_hh, q_w, rnn_state, memory, context,
                                             a_w, loc_w, a_b, loc_b, atten, conv_w,
                                             Wihb, Whhb, qwb, X2b, X1b, Bbig, ebias, Lconv);
    // GRU: N=6144 (gi|gh), 48 N-tiles x K-split4 = 192 blocks, Klen=256
    k_gemm_ks<<<192, 256, 0, stream>>>(X1b, X2b, Wihb, Whhb, Cgru, 6144, 48, 3072, 1024, 256);
    k_gates<<<256, 256, 0, stream>>>(Cgru, rnn_state, b_ih, b_hh, out, X3b);
    // pq: N=512, 4 N-tiles x K-split4 = 16 blocks, Klen=256
    k_gemm_ks<<<16, 256, 0, stream>>>(X3b, X3b, qwb, qwb, pqP, 512, 4, 0x40000000, 1024, 256);
    k_attn<<<2048, 256, 0, stream>>>(annots, Lconv, Bbig, pqP, q_b, ebias, v_w, wsal);
    k_ctx<<<512, 256, 0, stream>>>(annots, wsal, mask, out);
}